// Round 6
// baseline (230.818 us; speedup 1.0000x reference)
//
#include <hip/hip_runtime.h>
#include <hip/hip_bf16.h>

typedef unsigned short u16;
typedef __attribute__((ext_vector_type(8))) short short8;
typedef __attribute__((ext_vector_type(4))) short short4v;
typedef __attribute__((ext_vector_type(4))) float f32x4;

#define NB 8
#define TT 1024
#define DD 512
#define UU 512
#define HH 8
#define DH 64
#define SCALE 0.044194173824159216f  // 1/sqrt(512)
#define MASK_FILL -1000000.0f

__device__ __forceinline__ float ld_flex(const void* p, long i, bool f32) {
  if (f32) return ((const float*)p)[i];
  unsigned int u = (unsigned int)(((const u16*)p)[i]) << 16;
  return __uint_as_float(u);
}

__device__ __forceinline__ u16 f32_to_bf16(float f) {
  unsigned int u = __float_as_uint(f);
  unsigned int r = (u + 0x7FFFu + ((u >> 16) & 1u)) >> 16;  // RNE
  return (u16)r;
}

// 16x16x16 bf16 MFMA: builtin name varies across ROCm versions
__device__ __forceinline__ f32x4 mfma16_bf16(short4v a, short4v b, f32x4 c) {
#if __has_builtin(__builtin_amdgcn_mfma_f32_16x16x16bf16_1k)
  return __builtin_amdgcn_mfma_f32_16x16x16bf16_1k(a, b, c, 0, 0, 0);
#elif __has_builtin(__builtin_amdgcn_mfma_f32_16x16x16_bf16)
  return __builtin_amdgcn_mfma_f32_16x16x16_bf16(a, b, c, 0, 0, 0);
#else
  f32x4 d;
  asm volatile("v_mfma_f32_16x16x16_bf16 %0, %1, %2, %3"
               : "=v"(d) : "v"(a), "v"(b), "0"(c));
  return d;
#endif
}

// async 16B global -> LDS (wave-uniform LDS base + lane*16)
__device__ __forceinline__ void gld16(const void* g, void* l) {
  __builtin_amdgcn_global_load_lds(
      (const __attribute__((address_space(1))) unsigned int*)g,
      (__attribute__((address_space(3))) unsigned int*)l, 16, 0, 0);
}

// ---------- probe: input dtype + mask layout; also build maskadd ----------
__global__ void probe_kernel(const void* __restrict__ qptr,
                             const void* __restrict__ mptr,
                             int* __restrict__ flags,
                             float* __restrict__ maskadd) {
  __shared__ int s_f32, s_mi32;
  if (threadIdx.x == 0) { s_f32 = 0; s_mi32 = 1; }
  __syncthreads();
  const u16* qh = (const u16*)qptr;
  int weird = 0;
  for (int i = threadIdx.x; i < 4096; i += 256) {
    unsigned int u = (unsigned int)qh[i] << 16;
    float v = __uint_as_float(u);
    if (!(v == v) || fabsf(v) > 1e6f) weird = 1;
  }
  if (weird) atomicOr(&s_f32, 1);
  const unsigned int* mi = (const unsigned int*)mptr;
  int bad = 0;
  for (int i = threadIdx.x; i < 2048; i += 256) {
    if (mi[i] > 1u) bad = 1;
  }
  if (bad) atomicAnd(&s_mi32, 0);
  __syncthreads();
  if (threadIdx.x == 0) { flags[0] = s_f32; flags[1] = s_mi32; }
  const bool mi32 = (s_mi32 != 0);
  const int* mw = (const int*)mptr;
  const unsigned char* mb = (const unsigned char*)mptr;
  for (int i = threadIdx.x; i < NB * TT; i += 256) {
    bool mv = mi32 ? (mw[i] != 0) : (mb[i] != 0);
    maskadd[i] = mv ? 0.0f : MASK_FILL;
  }
}

// ---------- convert fp32/bf16 input -> bf16 (y picks query/key) ----------
__global__ __launch_bounds__(256) void convert_bf16(
    const void* __restrict__ query, const void* __restrict__ key,
    u16* __restrict__ Xq, u16* __restrict__ Xk,
    const int* __restrict__ flags) {
  const bool f32 = flags[0] != 0;
  const void* in = blockIdx.y ? key : query;
  u16* out = blockIdx.y ? Xk : Xq;
  int i = blockIdx.x * 256 + threadIdx.x;
  ushort4 o;
  if (f32) {
    float4 v = ((const float4*)in)[i];
    o.x = f32_to_bf16(v.x); o.y = f32_to_bf16(v.y);
    o.z = f32_to_bf16(v.z); o.w = f32_to_bf16(v.w);
  } else {
    o = ((const ushort4*)in)[i];
  }
  ((ushort4*)out)[i] = o;
}

// ---------- weight transpose: Wt[n][k] = W[k][n], bf16; Wq pre-scaled ----------
__global__ __launch_bounds__(256) void wtrans(
    const void* __restrict__ W0, const void* __restrict__ W1,
    const void* __restrict__ W2, u16* __restrict__ Wt,
    const int* __restrict__ flags) {
  const bool f32 = flags[0] != 0;
  const void* W = (blockIdx.z == 0) ? W0 : (blockIdx.z == 1) ? W1 : W2;
  const float sc = (blockIdx.z == 0) ? SCALE : 1.0f;
  u16* out = Wt + (size_t)blockIdx.z * DD * UU;
  __shared__ float tile[32][33];
  const int k0 = blockIdx.x * 32, n0 = blockIdx.y * 32;
  const int tid = threadIdx.x;
#pragma unroll
  for (int p = 0; p < 4; ++p) {
    int i = (tid >> 5) + p * 8, j = tid & 31;
    tile[i][j] = ld_flex(W, (long)(k0 + i) * UU + n0 + j, f32);
  }
  __syncthreads();
#pragma unroll
  for (int p = 0; p < 4; ++p) {
    int nl = (tid >> 5) + p * 8, kl = tid & 31;
    out[(size_t)(n0 + nl) * DD + k0 + kl] = f32_to_bf16(tile[kl][nl] * sc);
  }
}

// ---------- m97-style projection GEMM: 128x128 tile, LDS-staged, 4 waves ----------
// z picks {Q,K,V}. C = X[8192x512] @ Wt^T (Wt is [n][k]).
__global__ __launch_bounds__(256) void proj_mfma(
    const u16* __restrict__ Xq, const u16* __restrict__ Xk,
    const u16* __restrict__ Wt, u16* __restrict__ Qp, u16* __restrict__ Kp,
    u16* __restrict__ Vt) {
  __shared__ __align__(16) u16 As[128 * 32];  // [row][k] 64B rows
  __shared__ __align__(16) u16 Bs[128 * 32];
  const int z = blockIdx.z;
  const u16* X = (z == 0) ? Xq : Xk;
  const u16* Wz = Wt + (size_t)z * DD * UU;
  const int m0 = blockIdx.x * 128, n0 = blockIdx.y * 128;
  const int tid = threadIdx.x;
  const int w = tid >> 6, l = tid & 63;
  const int quad = l >> 4, l15 = l & 15;
  const int wm = (w >> 1) * 64, wn = (w & 1) * 64;

  // per-lane staging source row/col (chunk c = w*128 + i*64 + l)
  const int c0 = w * 128 + l;
  const int row0 = c0 >> 2, q0 = (c0 & 3) * 8;
  const int c1 = c0 + 64;
  const int row1 = c1 >> 2, q1 = (c1 & 3) * 8;
  const u16* aS0 = X + (size_t)(m0 + row0) * DD + q0;
  const u16* aS1 = X + (size_t)(m0 + row1) * DD + q1;
  const u16* bS0 = Wz + (size_t)(n0 + row0) * DD + q0;
  const u16* bS1 = Wz + (size_t)(n0 + row1) * DD + q1;
  u16* aD0 = &As[(size_t)(w * 128) * 8];
  u16* aD1 = &As[(size_t)(w * 128 + 64) * 8];
  u16* bD0 = &Bs[(size_t)(w * 128) * 8];
  u16* bD1 = &Bs[(size_t)(w * 128 + 64) * 8];

  f32x4 acc[4][4];
#pragma unroll
  for (int mi = 0; mi < 4; ++mi)
#pragma unroll
    for (int ni = 0; ni < 4; ++ni)
#pragma unroll
      for (int r = 0; r < 4; ++r) acc[mi][ni][r] = 0.0f;

  for (int k0 = 0; k0 < DD; k0 += 32) {
    gld16(aS0 + k0, aD0);
    gld16(aS1 + k0, aD1);
    gld16(bS0 + k0, bD0);
    gld16(bS1 + k0, bD1);
    __syncthreads();
    short8 af[4], bf[4];
#pragma unroll
    for (int mi = 0; mi < 4; ++mi)
      af[mi] = *(const short8*)&As[(wm + mi * 16 + l15) * 32 + quad * 8];
#pragma unroll
    for (int ni = 0; ni < 4; ++ni)
      bf[ni] = *(const short8*)&Bs[(wn + ni * 16 + l15) * 32 + quad * 8];
#pragma unroll
    for (int mi = 0; mi < 4; ++mi)
#pragma unroll
      for (int ni = 0; ni < 4; ++ni)
        acc[mi][ni] = __builtin_amdgcn_mfma_f32_16x16x32_bf16(
            af[mi], bf[ni], acc[mi][ni], 0, 0, 0);
    __syncthreads();
  }

  if (z < 2) {
    u16* out = (z == 0) ? Qp : Kp;
#pragma unroll
    for (int mi = 0; mi < 4; ++mi)
#pragma unroll
      for (int ni = 0; ni < 4; ++ni)
#pragma unroll
        for (int r = 0; r < 4; ++r) {
          int m = m0 + wm + mi * 16 + quad * 4 + r;
          int u = n0 + wn + ni * 16 + l15;
          out[(size_t)m * UU + u] = f32_to_bf16(acc[mi][ni][r]);
        }
  } else {
#pragma unroll
    for (int mi = 0; mi < 4; ++mi)
#pragma unroll
      for (int ni = 0; ni < 4; ++ni) {
        int m = m0 + wm + mi * 16 + quad * 4;  // tk base (r consecutive)
        int nb = m >> 10, tk = m & 1023;
        int u = n0 + wn + ni * 16 + l15;
        int h = u >> 6, dh = u & 63;
        ushort4 pk;
        pk.x = f32_to_bf16(acc[mi][ni][0]);
        pk.y = f32_to_bf16(acc[mi][ni][1]);
        pk.z = f32_to_bf16(acc[mi][ni][2]);
        pk.w = f32_to_bf16(acc[mi][ni][3]);
        *(ushort4*)&Vt[(size_t)((nb * HH + h) * DH + dh) * TT + tk] = pk;
      }
  }
}

// ---------- attention: 4-wave k-split, register-resident P ----------
// S^T[key][q] = K.Q^T via 16x16x32 (A=K, B=Q). C-layout row quad*4+r equals the
// 16x16x16 A/B k-mapping quad*4+j, so exp'd S^T packs directly into the PV
// B-operand: O^T[dh][q] += V^T-A-frag x P-frag. No LDS in the main loop.
// Fixed-base softmax (exact: |logits| <~ 3; masked keys -> exp(-1e6) = 0).
__global__ __launch_bounds__(256) void attn_mfma(
    const u16* __restrict__ Qp, const u16* __restrict__ Kp,
    const u16* __restrict__ Vt, const float* __restrict__ maskadd,
    void* __restrict__ out, const int* __restrict__ flags) {
  // cbuf 4 waves x [32 dh][33] f32 = 16896 B | lp 4x32 f32 at +16896 -> 17408 B
  __shared__ __align__(16) char smem[17408];
  const int tid = threadIdx.x;
  const int w = tid >> 6, l = tid & 63;
  const int quad = l >> 4, l15 = l & 15;
  const int qt = blockIdx.x, h = blockIdx.y, n = blockIdx.z;
  const int q0 = qt * 32;
  const bool f32o = flags[0] != 0;

  // Q as B-operand frags: bq[nq][kd], lane l15 = q, k = kd*32 + quad*8 + j
  const u16* qbase = Qp + (size_t)(n * TT + q0 + l15) * UU + h * DH + quad * 8;
  short8 bq[2][2];
  bq[0][0] = *(const short8*)(qbase);
  bq[0][1] = *(const short8*)(qbase + 32);
  bq[1][0] = *(const short8*)(qbase + 16 * UU);
  bq[1][1] = *(const short8*)(qbase + 16 * UU + 32);

  // K as A-operand: lane l15 = key row, k = kd*32 + quad*8 + j
  const u16* kbase = Kp + (size_t)(n * TT + l15) * UU + h * DH + quad * 8;
  // V^T as A-operand for 16x16x16: lane l15 = dh row, k = quad*4 + j
  const u16* vbase = Vt + (size_t)((n * HH + h) * DH + l15) * TT + quad * 4;
  const float* mbase = maskadd + n * TT;

  f32x4 o[4][2];  // [dh-tile][q-tile]
  float lsum[2] = {0.0f, 0.0f};
#pragma unroll
  for (int mi = 0; mi < 4; ++mi)
#pragma unroll
    for (int nq = 0; nq < 2; ++nq)
#pragma unroll
      for (int r = 0; r < 4; ++r) o[mi][nq][r] = 0.0f;

  // preload first K tile: ak[kt][kd], key = kb + kt*16 + l15
  short8 ak[2][2], akn[2][2];
#pragma unroll
  for (int kt = 0; kt < 2; ++kt)
#pragma unroll
    for (int kd = 0; kd < 2; ++kd)
      ak[kt][kd] = *(const short8*)(kbase + (size_t)(w * 256 + kt * 16) * UU + kd * 32);

  const int kend = w * 256 + 256;
  for (int kb = w * 256; kb < kend; kb += 32) {
    // V A-frags: av[mi][kt], dh = mi*16 + l15, keys kb + kt*16 + quad*4 + j
    short4v av[4][2];
#pragma unroll
    for (int mi = 0; mi < 4; ++mi)
#pragma unroll
      for (int kt = 0; kt < 2; ++kt)
        av[mi][kt] = *(const short4v*)(vbase + (size_t)(mi * 16) * TT + kb + kt * 16);
    // mask per key-row: rows quad*4+r
    float4 mk[2];
#pragma unroll
    for (int kt = 0; kt < 2; ++kt)
      mk[kt] = *(const float4*)&mbase[kb + kt * 16 + quad * 4];
    // prefetch next K tile
    const int kb2 = (kb + 32) & (TT - 1);
#pragma unroll
    for (int kt = 0; kt < 2; ++kt)
#pragma unroll
      for (int kd = 0; kd < 2; ++kd)
        akn[kt][kd] = *(const short8*)(kbase + (size_t)(kb2 + kt * 16) * UU + kd * 32);

    // S^T = K Q^T  (rows=key, cols=q); Q pre-scaled by 1/sqrt(512)
    f32x4 s[2][2];
#pragma unroll
    for (int kt = 0; kt < 2; ++kt)
#pragma unroll
      for (int nq = 0; nq < 2; ++nq) {
#pragma unroll
        for (int r = 0; r < 4; ++r) s[kt][nq][r] = 0.0f;
#pragma unroll
        for (int kd = 0; kd < 2; ++kd)
          s[kt][nq] = __builtin_amdgcn_mfma_f32_16x16x32_bf16(
              ak[kt][kd], bq[nq][kd], s[kt][nq], 0, 0, 0);
      }

    // P = exp(S^T + mask[row]); pack straight into PV B-frags (no lane movement)
    short4v p[2][2];
#pragma unroll
    for (int kt = 0; kt < 2; ++kt)
#pragma unroll
      for (int nq = 0; nq < 2; ++nq) {
        float e0 = __expf(s[kt][nq][0] + mk[kt].x);
        float e1 = __expf(s[kt][nq][1] + mk[kt].y);
        float e2 = __expf(s[kt][nq][2] + mk[kt].z);
        float e3 = __expf(s[kt][nq][3] + mk[kt].w);
        lsum[nq] += (e0 + e1) + (e2 + e3);
        union { __hip_bfloat162 h2; unsigned int u; } c01, c23;
        c01.h2 = __float22bfloat162_rn(make_float2(e0, e1));
        c23.h2 = __float22bfloat162_rn(make_float2(e2, e3));
        union { short4v s4; unsigned int u[2]; } pk;
        pk.u[0] = c01.u; pk.u[1] = c23.u;
        p[kt][nq] = pk.s4;
      }

    // O^T += V^T P   (16x16x16)
#pragma unroll
    for (int mi = 0; mi < 4; ++mi)
#pragma unroll
      for (int nq = 0; nq < 2; ++nq)
#pragma unroll
        for (int kt = 0; kt < 2; ++kt)
          o[mi][nq] = mfma16_bf16(av[mi][kt], p[kt][nq], o[mi][nq]);

#pragma unroll
    for (int kt = 0; kt < 2; ++kt)
#pragma unroll
      for (int kd = 0; kd < 2; ++kd) ak[kt][kd] = akn[kt][kd];
  }

  // full per-wave row sums: butterfly across the 4 quads (lanes ^16, ^32)
#pragma unroll
  for (int nq = 0; nq < 2; ++nq) {
    lsum[nq] += __shfl_xor(lsum[nq], 16);
    lsum[nq] += __shfl_xor(lsum[nq], 32);
  }

  float* cbuf = (float*)smem;              // [w][32][33]
  float* lp = (float*)(smem + 16896);      // [4][32]
  if (quad == 0) {
    lp[w * 32 + l15] = lsum[0];
    lp[w * 32 + 16 + l15] = lsum[1];
  }

  // chunked O^T merge: 2 chunks of 32 dh rows
  float* Ow = cbuf + w * (32 * 33);
#pragma unroll
  for (int c = 0; c < 2; ++c) {
#pragma unroll
    for (int mi2 = 0; mi2 < 2; ++mi2)
#pragma unroll
      for (int nq = 0; nq < 2; ++nq)
#pragma unroll
        for (int r = 0; r < 4; ++r)
          Ow[(mi2 * 16 + quad * 4 + r) * 33 + nq * 16 + l15] = o[c * 2 + mi2][nq][r];
    __syncthreads();
    for (int i = tid; i < 32 * 32; i += 256) {
      int q = i >> 5, dh = i & 31;
      float s = cbuf[0 * 1056 + dh * 33 + q] + cbuf[1 * 1056 + dh * 33 + q] +
                cbuf[2 * 1056 + dh * 33 + q] + cbuf[3 * 1056 + dh * 33 + q];
      float ls = lp[q] + lp[32 + q] + lp[64 + q] + lp[96 + q];
      float v = s / ls;
      size_t idx = (size_t)(n * TT + q0 + q) * UU + h * DH + c * 32 + dh;
      if (f32o) ((float*)out)[idx] = v;
      else ((u16*)out)[idx] = f32_to_bf16(v);
    }
    __syncthreads();
  }
}

// ---------- launcher ----------
extern "C" void kernel_launch(void* const* d_in, const int* in_sizes, int n_in,
                              void* d_out, int out_size, void* d_ws, size_t ws_size,
                              hipStream_t stream) {
  const void* query = d_in[0];
  const void* key   = d_in[1];
  const void* mask  = d_in[2];
  const void* Wq    = d_in[3];
  const void* Wk    = d_in[4];
  const void* Wv    = d_in[5];

  char* base = (char*)d_ws;
  int* flags = (int*)base;
  float* maskadd = (float*)(base + 256);                  // 32 KB
  u16* Wt  = (u16*)(base + 64 * 1024);                    // 1.5 MB
  u16* Xq  = Wt + (size_t)3 * DD * UU;                    // 8 MB
  u16* Xk  = Xq + (size_t)NB * TT * DD;                   // 8 MB
  u16* Qp  = Xk + (size_t)NB * TT * DD;                   // 8 MB
  u16* Kp  = Qp + (size_t)NB * TT * UU;                   // 8 MB
  u16* Vtp = Kp + (size_t)NB * TT * UU;                   // 8 MB

  probe_kernel<<<1, 256, 0, stream>>>(query, mask, flags, maskadd);
  wtrans<<<dim3(16, 16, 3), 256, 0, stream>>>(Wq, Wk, Wv, Wt, flags);
  convert_bf16<<<dim3(NB * TT * DD / 4 / 256, 2), 256, 0, stream>>>(
      query, key, Xq, Xk, flags);

  dim3 pgrid(NB * TT / 128, UU / 128, 3);  // (64, 4, 3)
  proj_mfma<<<pgrid, 256, 0, stream>>>(Xq, Xk, Wt, Qp, Kp, Vtp);

  dim3 agrid(TT / 32, HH, NB);  // (32, 8, 8)
  attn_mfma<<<agrid, 256, 0, stream>>>(Qp, Kp, Vtp, maskadd, d_out, flags);
}

// Round 7
// 197.172 us; speedup vs baseline: 1.1706x; 1.1706x over previous
//
#include <hip/hip_runtime.h>
#include <hip/hip_bf16.h>

typedef unsigned short u16;
typedef __attribute__((ext_vector_type(8))) short short8;
typedef __attribute__((ext_vector_type(4))) short short4v;
typedef __attribute__((ext_vector_type(4))) float f32x4;

#define NB 8
#define TT 1024
#define DD 512
#define UU 512
#define HH 8
#define DH 64
#define SCALE 0.044194173824159216f   // 1/sqrt(512)
#define LOG2E 1.4426950408889634f
#define MASK_FILL_2 -1442695.0f       // -1e6 * log2e (exp2 domain)

__device__ __forceinline__ float ld_flex(const void* p, long i, bool f32) {
  if (f32) return ((const float*)p)[i];
  unsigned int u = (unsigned int)(((const u16*)p)[i]) << 16;
  return __uint_as_float(u);
}

__device__ __forceinline__ u16 f32_to_bf16(float f) {
  unsigned int u = __float_as_uint(f);
  unsigned int r = (u + 0x7FFFu + ((u >> 16) & 1u)) >> 16;  // RNE
  return (u16)r;
}

__device__ __forceinline__ float ex2(float x) {
#if __has_builtin(__builtin_amdgcn_exp2f)
  return __builtin_amdgcn_exp2f(x);
#else
  return __expf(x * 0.6931471805599453f);
#endif
}

__device__ __forceinline__ unsigned int pk_bf16(float a, float b) {
  union { __hip_bfloat162 h2; unsigned int u; } c;
  c.h2 = __float22bfloat162_rn(make_float2(a, b));
  return c.u;
}

// async 16B global -> LDS (wave-uniform LDS base + lane*16)
__device__ __forceinline__ void gld16(const void* g, void* l) {
  __builtin_amdgcn_global_load_lds(
      (const __attribute__((address_space(1))) unsigned int*)g,
      (__attribute__((address_space(3))) unsigned int*)l, 16, 0, 0);
}

// ---------- probe: flags only (fast, minimal serialization) ----------
__global__ void probe_kernel(const void* __restrict__ qptr,
                             const void* __restrict__ mptr,
                             int* __restrict__ flags) {
  __shared__ int s_f32, s_mi32;
  if (threadIdx.x == 0) { s_f32 = 0; s_mi32 = 1; }
  __syncthreads();
  const u16* qh = (const u16*)qptr;
  int weird = 0;
  for (int i = threadIdx.x; i < 4096; i += 256) {
    unsigned int u = (unsigned int)qh[i] << 16;
    float v = __uint_as_float(u);
    if (!(v == v) || fabsf(v) > 1e6f) weird = 1;
  }
  if (weird) atomicOr(&s_f32, 1);
  const unsigned int* mi = (const unsigned int*)mptr;
  int bad = 0;
  for (int i = threadIdx.x; i < 2048; i += 256) {
    if (mi[i] > 1u) bad = 1;
  }
  if (bad) atomicAnd(&s_mi32, 0);
  __syncthreads();
  if (threadIdx.x == 0) { flags[0] = s_f32; flags[1] = s_mi32; }
}

// ---------- merged prep: convert (8192 blocks) | wtrans (768) | maskadd (32) ----------
#define CONV_BLOCKS 8192
#define WT_BLOCKS 768
#define MASK_BLOCKS 32

__global__ __launch_bounds__(256) void prep_kernel(
    const void* __restrict__ query, const void* __restrict__ key,
    const void* __restrict__ W0, const void* __restrict__ W1,
    const void* __restrict__ W2, const void* __restrict__ mask,
    u16* __restrict__ Xq, u16* __restrict__ Xk, u16* __restrict__ Wt,
    float* __restrict__ maskadd, const int* __restrict__ flags) {
  __shared__ float tile[32][33];
  const bool f32 = flags[0] != 0;
  const int b = blockIdx.x, tid = threadIdx.x;
  if (b < CONV_BLOCKS) {
    const void* in = (b < 4096) ? query : key;
    u16* out = (b < 4096) ? Xq : Xk;
    int i = (b & 4095) * 256 + tid;
    ushort4 o;
    if (f32) {
      float4 v = ((const float4*)in)[i];
      o.x = f32_to_bf16(v.x); o.y = f32_to_bf16(v.y);
      o.z = f32_to_bf16(v.z); o.w = f32_to_bf16(v.w);
    } else {
      o = ((const ushort4*)in)[i];
    }
    ((ushort4*)out)[i] = o;
  } else if (b < CONV_BLOCKS + WT_BLOCKS) {
    const int lb = b - CONV_BLOCKS;
    const int z = lb >> 8, rem = lb & 255;
    const int k0 = (rem & 15) * 32, n0 = (rem >> 4) * 32;
    const void* W = (z == 0) ? W0 : (z == 1) ? W1 : W2;
    const float sc = (z == 0) ? SCALE * LOG2E : 1.0f;  // fold softmax scale+log2e into Wq
    u16* out = Wt + (size_t)z * DD * UU;
#pragma unroll
    for (int p = 0; p < 4; ++p) {
      int i = (tid >> 5) + p * 8, j = tid & 31;
      tile[i][j] = ld_flex(W, (long)(k0 + i) * UU + n0 + j, f32);
    }
    __syncthreads();
#pragma unroll
    for (int p = 0; p < 4; ++p) {
      int nl = (tid >> 5) + p * 8, kl = tid & 31;
      out[(size_t)(n0 + nl) * DD + k0 + kl] = f32_to_bf16(tile[kl][nl] * sc);
    }
  } else {
    const int i = (b - CONV_BLOCKS - WT_BLOCKS) * 256 + tid;
    const bool mi32 = flags[1] != 0;
    bool mv = mi32 ? (((const int*)mask)[i] != 0)
                   : (((const unsigned char*)mask)[i] != 0);
    maskadd[i] = mv ? 0.0f : MASK_FILL_2;
  }
}

// ---------- m97-style projection GEMM: 128x128 tile, LDS-staged, 4 waves ----------
__global__ __launch_bounds__(256) void proj_mfma(
    const u16* __restrict__ Xq, const u16* __restrict__ Xk,
    const u16* __restrict__ Wt, u16* __restrict__ Qp, u16* __restrict__ Kp,
    u16* __restrict__ Vt) {
  __shared__ __align__(16) u16 As[128 * 32];  // [row][k] 64B rows
  __shared__ __align__(16) u16 Bs[128 * 32];
  const int z = blockIdx.z;
  const u16* X = (z == 0) ? Xq : Xk;
  const u16* Wz = Wt + (size_t)z * DD * UU;
  const int m0 = blockIdx.x * 128, n0 = blockIdx.y * 128;
  const int tid = threadIdx.x;
  const int w = tid >> 6, l = tid & 63;
  const int quad = l >> 4, l15 = l & 15;
  const int wm = (w >> 1) * 64, wn = (w & 1) * 64;

  const int c0 = w * 128 + l;
  const int row0 = c0 >> 2, q0 = (c0 & 3) * 8;
  const int c1 = c0 + 64;
  const int row1 = c1 >> 2, q1 = (c1 & 3) * 8;
  const u16* aS0 = X + (size_t)(m0 + row0) * DD + q0;
  const u16* aS1 = X + (size_t)(m0 + row1) * DD + q1;
  const u16* bS0 = Wz + (size_t)(n0 + row0) * DD + q0;
  const u16* bS1 = Wz + (size_t)(n0 + row1) * DD + q1;
  u16* aD0 = &As[(size_t)(w * 128) * 8];
  u16* aD1 = &As[(size_t)(w * 128 + 64) * 8];
  u16* bD0 = &Bs[(size_t)(w * 128) * 8];
  u16* bD1 = &Bs[(size_t)(w * 128 + 64) * 8];

  f32x4 acc[4][4];
#pragma unroll
  for (int mi = 0; mi < 4; ++mi)
#pragma unroll
    for (int ni = 0; ni < 4; ++ni)
#pragma unroll
      for (int r = 0; r < 4; ++r) acc[mi][ni][r] = 0.0f;

  for (int k0 = 0; k0 < DD; k0 += 32) {
    gld16(aS0 + k0, aD0);
    gld16(aS1 + k0, aD1);
    gld16(bS0 + k0, bD0);
    gld16(bS1 + k0, bD1);
    __syncthreads();
    short8 af[4], bf[4];
#pragma unroll
    for (int mi = 0; mi < 4; ++mi)
      af[mi] = *(const short8*)&As[(wm + mi * 16 + l15) * 32 + quad * 8];
#pragma unroll
    for (int ni = 0; ni < 4; ++ni)
      bf[ni] = *(const short8*)&Bs[(wn + ni * 16 + l15) * 32 + quad * 8];
#pragma unroll
    for (int mi = 0; mi < 4; ++mi)
#pragma unroll
      for (int ni = 0; ni < 4; ++ni)
        acc[mi][ni] = __builtin_amdgcn_mfma_f32_16x16x32_bf16(
            af[mi], bf[ni], acc[mi][ni], 0, 0, 0);
    __syncthreads();
  }

  if (z < 2) {
    u16* out = (z == 0) ? Qp : Kp;
#pragma unroll
    for (int mi = 0; mi < 4; ++mi)
#pragma unroll
      for (int ni = 0; ni < 4; ++ni)
#pragma unroll
        for (int r = 0; r < 4; ++r) {
          int m = m0 + wm + mi * 16 + quad * 4 + r;
          int u = n0 + wn + ni * 16 + l15;
          out[(size_t)m * UU + u] = f32_to_bf16(acc[mi][ni][r]);
        }
  } else {
#pragma unroll
    for (int mi = 0; mi < 4; ++mi)
#pragma unroll
      for (int ni = 0; ni < 4; ++ni) {
        int m = m0 + wm + mi * 16 + quad * 4;
        int nb = m >> 10, tk = m & 1023;
        int u = n0 + wn + ni * 16 + l15;
        int h = u >> 6, dh = u & 63;
        ushort4 pk;
        pk.x = f32_to_bf16(acc[mi][ni][0]);
        pk.y = f32_to_bf16(acc[mi][ni][1]);
        pk.z = f32_to_bf16(acc[mi][ni][2]);
        pk.w = f32_to_bf16(acc[mi][ni][3]);
        *(ushort4*)&Vt[(size_t)((nb * HH + h) * DH + dh) * TT + tk] = pk;
      }
  }
}

// ---------- attention: 4-wave k-split, S^T orientation + packed P^T round-trip ----------
// S^T = K.Q^T (A=K, B=Q): lane holds 4 CONSECUTIVE keys for one q, so P^T[q][key]
// writes are 1 ds_write_b64 + 2 cvt_pk per (kt,nq). PV stays full-K 16x16x32:
// A = P^T rows (q=l15, keys quad*8+j), B = V^T rows (dh=l15, keys quad*8+j).
// Fixed-base softmax in exp2 domain (Wq pre-scaled by SCALE*log2e; mask adds -1.44e6).
__global__ __launch_bounds__(256) void attn_mfma(
    const u16* __restrict__ Qp, const u16* __restrict__ Kp,
    const u16* __restrict__ Vt, const float* __restrict__ maskadd,
    void* __restrict__ out, const int* __restrict__ flags) {
  // Pbuf 4 waves x [32 q][36 key-stride] u16 = 9216 B (loop)
  // union with epilogue: cbuf 4 x 16 x 68 f32 = 17408 B | lp 128 f32 -> 17920 B
  __shared__ __align__(16) char smem[17920];
  const int tid = threadIdx.x;
  const int w = tid >> 6, l = tid & 63;
  const int quad = l >> 4, l15 = l & 15;
  const int qt = blockIdx.x, h = blockIdx.y, n = blockIdx.z;
  const int q0 = qt * 32;
  const bool f32o = flags[0] != 0;
  u16* Pw = (u16*)smem + w * (32 * 36);

  // Q as B-frags: q = nq*16 + l15, d = kd*32 + quad*8 + j
  const u16* qbase = Qp + (size_t)(n * TT + q0 + l15) * UU + h * DH + quad * 8;
  short8 bq[2][2];
  bq[0][0] = *(const short8*)(qbase);
  bq[0][1] = *(const short8*)(qbase + 32);
  bq[1][0] = *(const short8*)(qbase + 16 * UU);
  bq[1][1] = *(const short8*)(qbase + 16 * UU + 32);

  const u16* kbase = Kp + (size_t)(n * TT + l15) * UU + h * DH + quad * 8;
  const u16* vbase = Vt + (size_t)((n * HH + h) * DH + l15) * TT + quad * 8;
  const float* mbase = maskadd + n * TT;

  f32x4 o[2][4];  // [q-tile][dh-tile]
  float lsum[2] = {0.0f, 0.0f};
#pragma unroll
  for (int nq = 0; nq < 2; ++nq)
#pragma unroll
    for (int ni = 0; ni < 4; ++ni)
#pragma unroll
      for (int r = 0; r < 4; ++r) o[nq][ni][r] = 0.0f;

  // preload first K/V tiles
  short8 ak[2][2], vf[4];
#pragma unroll
  for (int kt = 0; kt < 2; ++kt)
#pragma unroll
    for (int kd = 0; kd < 2; ++kd)
      ak[kt][kd] = *(const short8*)(kbase + (size_t)(w * 256 + kt * 16) * UU + kd * 32);
#pragma unroll
  for (int ni = 0; ni < 4; ++ni)
    vf[ni] = *(const short8*)(vbase + (size_t)(ni * 16) * TT + w * 256);

#pragma unroll
  for (int it = 0; it < 8; ++it) {
    const int kb = w * 256 + it * 32;
    const int kb2 = w * 256 + ((it * 32 + 32) & 255);
    // prefetch next K/V tiles (consumed next iteration)
    short8 akn[2][2], vfn[4];
#pragma unroll
    for (int kt = 0; kt < 2; ++kt)
#pragma unroll
      for (int kd = 0; kd < 2; ++kd)
        akn[kt][kd] = *(const short8*)(kbase + (size_t)(kb2 + kt * 16) * UU + kd * 32);
#pragma unroll
    for (int ni = 0; ni < 4; ++ni)
      vfn[ni] = *(const short8*)(vbase + (size_t)(ni * 16) * TT + kb2);
    // mask per key row (quad*4 + r)
    float4 mk[2];
    mk[0] = *(const float4*)&mbase[kb + quad * 4];
    mk[1] = *(const float4*)&mbase[kb + 16 + quad * 4];

    // S^T = K Q^T: rows = keys (kt*16 + quad*4 + r), cols = q (nq*16 + l15)
    f32x4 s[2][2];
#pragma unroll
    for (int kt = 0; kt < 2; ++kt)
#pragma unroll
      for (int nq = 0; nq < 2; ++nq) {
#pragma unroll
        for (int r = 0; r < 4; ++r) s[kt][nq][r] = 0.0f;
#pragma unroll
        for (int kd = 0; kd < 2; ++kd)
          s[kt][nq] = __builtin_amdgcn_mfma_f32_16x16x32_bf16(
              ak[kt][kd], bq[nq][kd], s[kt][nq], 0, 0, 0);
      }

    // P = exp2(S^T + mask); 4 consecutive keys per lane -> packed b64 write
#pragma unroll
    for (int kt = 0; kt < 2; ++kt)
#pragma unroll
      for (int nq = 0; nq < 2; ++nq) {
        float e0 = ex2(s[kt][nq][0] + mk[kt].x);
        float e1 = ex2(s[kt][nq][1] + mk[kt].y);
        float e2 = ex2(s[kt][nq][2] + mk[kt].z);
        float e3 = ex2(s[kt][nq][3] + mk[kt].w);
        lsum[nq] += (e0 + e1) + (e2 + e3);
        uint2 pk = make_uint2(pk_bf16(e0, e1), pk_bf16(e2, e3));
        *(uint2*)&Pw[(nq * 16 + l15) * 36 + kt * 16 + quad * 4] = pk;
      }

    // P^T A-frags: q = nq*16 + l15, keys quad*8..+7 (two b64, 8-aligned)
    short8 ap[2];
#pragma unroll
    for (int nq = 0; nq < 2; ++nq) {
      short4v lo = *(const short4v*)&Pw[(nq * 16 + l15) * 36 + quad * 8];
      short4v hi = *(const short4v*)&Pw[(nq * 16 + l15) * 36 + quad * 8 + 4];
      union { short8 v8; short4v v4[2]; } u;
      u.v4[0] = lo; u.v4[1] = hi;
      ap[nq] = u.v8;
    }

    // O += P V (16x16x32): C col = dh (l15), row = q (quad*4+r)
#pragma unroll
    for (int nq = 0; nq < 2; ++nq)
#pragma unroll
      for (int ni = 0; ni < 4; ++ni)
        o[nq][ni] = __builtin_amdgcn_mfma_f32_16x16x32_bf16(
            ap[nq], vf[ni], o[nq][ni], 0, 0, 0);

#pragma unroll
    for (int kt = 0; kt < 2; ++kt)
#pragma unroll
      for (int kd = 0; kd < 2; ++kd) ak[kt][kd] = akn[kt][kd];
#pragma unroll
    for (int ni = 0; ni < 4; ++ni) vf[ni] = vfn[ni];
  }

  // per-wave row sums: butterfly across the 4 quads
#pragma unroll
  for (int nq = 0; nq < 2; ++nq) {
    lsum[nq] += __shfl_xor(lsum[nq], 16);
    lsum[nq] += __shfl_xor(lsum[nq], 32);
  }

  float* lp = (float*)(smem + 17408);  // disjoint from Pbuf and cbuf
  if (quad == 0) {
    lp[w * 32 + l15] = lsum[0];
    lp[w * 32 + 16 + l15] = lsum[1];
  }
  __syncthreads();  // Pbuf region about to be reused as cbuf

  // chunked O-partial merge: 2 chunks of 16 q-rows, 4 x 16 x 68 f32 buffer
  float* cbuf = (float*)smem;
#pragma unroll
  for (int c = 0; c < 2; ++c) {
    float* Ow = cbuf + w * (16 * 68);
#pragma unroll
    for (int ni = 0; ni < 4; ++ni)
#pragma unroll
      for (int r = 0; r < 4; ++r)
        Ow[(quad * 4 + r) * 68 + ni * 16 + l15] = o[c][ni][r];
    __syncthreads();
    for (int i = tid; i < 16 * 64; i += 256) {
      int q = i >> 6, j = i & 63;
      float s = cbuf[0 * 1088 + q * 68 + j] + cbuf[1 * 1088 + q * 68 + j] +
                cbuf[2 * 1088 + q * 68 + j] + cbuf[3 * 1088 + q * 68 + j];
      int qg = c * 16 + q;
      float lsum4 = lp[qg] + lp[32 + qg] + lp[64 + qg] + lp[96 + qg];
      float v = s / lsum4;
      size_t idx = (size_t)(n * TT + q0 + qg) * UU + h * DH + j;
      if (f32o) ((float*)out)[idx] = v;
      else ((u16*)out)[idx] = f32_to_bf16(v);
    }
    __syncthreads();
  }
}

// ---------- launcher ----------
extern "C" void kernel_launch(void* const* d_in, const int* in_sizes, int n_in,
                              void* d_out, int out_size, void* d_ws, size_t ws_size,
                              hipStream_t stream) {
  const void* query = d_in[0];
  const void* key   = d_in[1];
  const void* mask  = d_in[2];
  const void* Wq    = d_in[3];
  const void* Wk    = d_in[4];
  const void* Wv    = d_in[5];

  char* base = (char*)d_ws;
  int* flags = (int*)base;
  float* maskadd = (float*)(base + 256);                  // 32 KB
  u16* Wt  = (u16*)(base + 64 * 1024);                    // 1.5 MB
  u16* Xq  = Wt + (size_t)3 * DD * UU;                    // 8 MB
  u16* Xk  = Xq + (size_t)NB * TT * DD;                   // 8 MB
  u16* Qp  = Xk + (size_t)NB * TT * DD;                   // 8 MB
  u16* Kp  = Qp + (size_t)NB * TT * UU;                   // 8 MB
  u16* Vtp = Kp + (size_t)NB * TT * UU;                   // 8 MB

  probe_kernel<<<1, 256, 0, stream>>>(query, mask, flags);
  prep_kernel<<<CONV_BLOCKS + WT_BLOCKS + MASK_BLOCKS, 256, 0, stream>>>(
      query, key, Wq, Wk, Wv, mask, Xq, Xk, Wt, maskadd, flags);

  dim3 pgrid(NB * TT / 128, UU / 128, 3);  // (64, 4, 3)
  proj_mfma<<<pgrid, 256, 0, stream>>>(Xq, Xk, Wt, Qp, Kp, Vtp);

  dim3 agrid(TT / 32, HH, NB);  // (32, 8, 8)
  attn_mfma<<<agrid, 256, 0, stream>>>(Qp, Kp, Vtp, maskadd, d_out, flags);
}

// Round 8
// 187.659 us; speedup vs baseline: 1.2300x; 1.0507x over previous
//
#include <hip/hip_runtime.h>
#include <hip/hip_bf16.h>

typedef unsigned short u16;
typedef __attribute__((ext_vector_type(8))) short short8;
typedef __attribute__((ext_vector_type(4))) short short4v;
typedef __attribute__((ext_vector_type(4))) float f32x4;

#define NB 8
#define TT 1024
#define DD 512
#define UU 512
#define HH 8
#define DH 64
#define SCALE 0.044194173824159216f   // 1/sqrt(512)
#define LOG2E 1.4426950408889634f
#define MASK_FILL_2 -1442695.0f       // -1e6 * log2e (exp2 domain)

__device__ __forceinline__ float ld_flex(const void* p, long i, bool f32) {
  if (f32) return ((const float*)p)[i];
  unsigned int u = (unsigned int)(((const u16*)p)[i]) << 16;
  return __uint_as_float(u);
}

__device__ __forceinline__ u16 f32_to_bf16(float f) {
  unsigned int u = __float_as_uint(f);
  unsigned int r = (u + 0x7FFFu + ((u >> 16) & 1u)) >> 16;  // RNE
  return (u16)r;
}

__device__ __forceinline__ float ex2(float x) {
#if __has_builtin(__builtin_amdgcn_exp2f)
  return __builtin_amdgcn_exp2f(x);
#else
  return __expf(x * 0.6931471805599453f);
#endif
}

__device__ __forceinline__ unsigned int pk_bf16(float a, float b) {
  union { __hip_bfloat162 h2; unsigned int u; } c;
  c.h2 = __float22bfloat162_rn(make_float2(a, b));
  return c.u;
}

// async 16B global -> LDS (wave-uniform LDS base + lane*16)
__device__ __forceinline__ void gld16(const void* g, void* l) {
  __builtin_amdgcn_global_load_lds(
      (const __attribute__((address_space(1))) unsigned int*)g,
      (__attribute__((address_space(3))) unsigned int*)l, 16, 0, 0);
}

// ---------- merged prep: convert | wtrans | maskadd, with inline probing ----------
#define CONV_BLOCKS 8192
#define WT_BLOCKS 768
#define MASK_BLOCKS 32

__global__ __launch_bounds__(256) void prep_kernel(
    const void* __restrict__ query, const void* __restrict__ key,
    const void* __restrict__ W0, const void* __restrict__ W1,
    const void* __restrict__ W2, const void* __restrict__ mask,
    u16* __restrict__ Xq, u16* __restrict__ Xk, u16* __restrict__ Wt,
    float* __restrict__ maskadd, int* __restrict__ flags) {
  __shared__ float tile[32][33];
  __shared__ int s_f32, s_mi32;
  const int b = blockIdx.x, tid = threadIdx.x;

  // ---- inline probe (every block; 2 KB of query + 2 KB of mask, L2-hot) ----
  if (tid == 0) { s_f32 = 0; s_mi32 = 1; }
  __syncthreads();
  {
    const u16* qh = (const u16*)query;
    int weird = 0;
#pragma unroll
    for (int p = 0; p < 4; ++p) {
      unsigned int u = (unsigned int)qh[tid * 4 + p] << 16;
      float v = __uint_as_float(u);
      if (!(v == v) || fabsf(v) > 1e6f) weird = 1;
    }
    if (weird) atomicOr(&s_f32, 1);
    const unsigned int* mi = (const unsigned int*)mask;
    if (mi[tid * 2] > 1u || mi[tid * 2 + 1] > 1u) atomicAnd(&s_mi32, 0);
  }
  __syncthreads();
  const bool f32 = s_f32 != 0;
  const bool mi32 = s_mi32 != 0;
  if (b == CONV_BLOCKS && tid == 0) { flags[0] = s_f32; flags[1] = s_mi32; }

  if (b < CONV_BLOCKS) {
    if (!f32) return;  // bf16 in memory: proj reads query/key directly
    const void* in = (b < 4096) ? query : key;
    u16* out = (b < 4096) ? Xq : Xk;
    int i = (b & 4095) * 256 + tid;
    float4 v = ((const float4*)in)[i];
    ushort4 o;
    o.x = f32_to_bf16(v.x); o.y = f32_to_bf16(v.y);
    o.z = f32_to_bf16(v.z); o.w = f32_to_bf16(v.w);
    ((ushort4*)out)[i] = o;
  } else if (b < CONV_BLOCKS + WT_BLOCKS) {
    const int lb = b - CONV_BLOCKS;
    const int z = lb >> 8, rem = lb & 255;
    const int k0 = (rem & 15) * 32, n0 = (rem >> 4) * 32;
    const void* W = (z == 0) ? W0 : (z == 1) ? W1 : W2;
    const float sc = (z == 0) ? SCALE * LOG2E : 1.0f;  // fold scale+log2e into Wq
    u16* out = Wt + (size_t)z * DD * UU;
#pragma unroll
    for (int p = 0; p < 4; ++p) {
      int i = (tid >> 5) + p * 8, j = tid & 31;
      tile[i][j] = ld_flex(W, (long)(k0 + i) * UU + n0 + j, f32);
    }
    __syncthreads();
#pragma unroll
    for (int p = 0; p < 4; ++p) {
      int nl = (tid >> 5) + p * 8, kl = tid & 31;
      out[(size_t)(n0 + nl) * DD + k0 + kl] = f32_to_bf16(tile[kl][nl] * sc);
    }
  } else {
    const int i = (b - CONV_BLOCKS - WT_BLOCKS) * 256 + tid;
    bool mv = mi32 ? (((const int*)mask)[i] != 0)
                   : (((const unsigned char*)mask)[i] != 0);
    maskadd[i] = mv ? 0.0f : MASK_FILL_2;
  }
}

// ---------- m97-style projection GEMM: 128x128 tile, LDS-staged, 4 waves ----------
__global__ __launch_bounds__(256) void proj_mfma(
    const void* __restrict__ query, const void* __restrict__ key,
    const u16* __restrict__ Xq, const u16* __restrict__ Xk,
    const u16* __restrict__ Wt, u16* __restrict__ Qp, u16* __restrict__ Kp,
    u16* __restrict__ Vt, const int* __restrict__ flags) {
  __shared__ __align__(16) u16 As[128 * 32];  // [row][k] 64B rows
  __shared__ __align__(16) u16 Bs[128 * 32];
  const bool f32 = flags[0] != 0;
  const int z = blockIdx.z;
  // bf16 inputs: stage straight from the input tensors (skip Xq/Xk round-trip)
  const u16* X = (z == 0) ? (f32 ? Xq : (const u16*)query)
                          : (f32 ? Xk : (const u16*)key);
  const u16* Wz = Wt + (size_t)z * DD * UU;
  const int m0 = blockIdx.x * 128, n0 = blockIdx.y * 128;
  const int tid = threadIdx.x;
  const int w = tid >> 6, l = tid & 63;
  const int quad = l >> 4, l15 = l & 15;
  const int wm = (w >> 1) * 64, wn = (w & 1) * 64;

  const int c0 = w * 128 + l;
  const int row0 = c0 >> 2, q0 = (c0 & 3) * 8;
  const int c1 = c0 + 64;
  const int row1 = c1 >> 2, q1 = (c1 & 3) * 8;
  const u16* aS0 = X + (size_t)(m0 + row0) * DD + q0;
  const u16* aS1 = X + (size_t)(m0 + row1) * DD + q1;
  const u16* bS0 = Wz + (size_t)(n0 + row0) * DD + q0;
  const u16* bS1 = Wz + (size_t)(n0 + row1) * DD + q1;
  u16* aD0 = &As[(size_t)(w * 128) * 8];
  u16* aD1 = &As[(size_t)(w * 128 + 64) * 8];
  u16* bD0 = &Bs[(size_t)(w * 128) * 8];
  u16* bD1 = &Bs[(size_t)(w * 128 + 64) * 8];

  f32x4 acc[4][4];
#pragma unroll
  for (int mi = 0; mi < 4; ++mi)
#pragma unroll
    for (int ni = 0; ni < 4; ++ni)
#pragma unroll
      for (int r = 0; r < 4; ++r) acc[mi][ni][r] = 0.0f;

  for (int k0 = 0; k0 < DD; k0 += 32) {
    gld16(aS0 + k0, aD0);
    gld16(aS1 + k0, aD1);
    gld16(bS0 + k0, bD0);
    gld16(bS1 + k0, bD1);
    __syncthreads();
    short8 af[4], bf[4];
#pragma unroll
    for (int mi = 0; mi < 4; ++mi)
      af[mi] = *(const short8*)&As[(wm + mi * 16 + l15) * 32 + quad * 8];
#pragma unroll
    for (int ni = 0; ni < 4; ++ni)
      bf[ni] = *(const short8*)&Bs[(wn + ni * 16 + l15) * 32 + quad * 8];
#pragma unroll
    for (int mi = 0; mi < 4; ++mi)
#pragma unroll
      for (int ni = 0; ni < 4; ++ni)
        acc[mi][ni] = __builtin_amdgcn_mfma_f32_16x16x32_bf16(
            af[mi], bf[ni], acc[mi][ni], 0, 0, 0);
    __syncthreads();
  }

  if (z < 2) {
    u16* out = (z == 0) ? Qp : Kp;
#pragma unroll
    for (int mi = 0; mi < 4; ++mi)
#pragma unroll
      for (int ni = 0; ni < 4; ++ni)
#pragma unroll
        for (int r = 0; r < 4; ++r) {
          int m = m0 + wm + mi * 16 + quad * 4 + r;
          int u = n0 + wn + ni * 16 + l15;
          out[(size_t)m * UU + u] = f32_to_bf16(acc[mi][ni][r]);
        }
  } else {
#pragma unroll
    for (int mi = 0; mi < 4; ++mi)
#pragma unroll
      for (int ni = 0; ni < 4; ++ni) {
        int m = m0 + wm + mi * 16 + quad * 4;
        int nb = m >> 10, tk = m & 1023;
        int u = n0 + wn + ni * 16 + l15;
        int h = u >> 6, dh = u & 63;
        ushort4 pk;
        pk.x = f32_to_bf16(acc[mi][ni][0]);
        pk.y = f32_to_bf16(acc[mi][ni][1]);
        pk.z = f32_to_bf16(acc[mi][ni][2]);
        pk.w = f32_to_bf16(acc[mi][ni][3]);
        *(ushort4*)&Vt[(size_t)((nb * HH + h) * DH + dh) * TT + tk] = pk;
      }
  }
}

// ---------- attention: 4-wave k-split, software-pipelined P round-trip ----------
// S^T = K.Q^T; P^T double-buffered in LDS. Iteration order:
//   read P[it]  ->  S[it+1] MFMA  ->  exp/write P[it+1]  ->  PV[it]
// so the write->read distance is a full iteration and read->use is covered by
// the S stage. Fixed-base softmax in exp2 domain (Wq pre-scaled by SCALE*log2e).
__global__ __launch_bounds__(256) void attn_mfma(
    const u16* __restrict__ Qp, const u16* __restrict__ Kp,
    const u16* __restrict__ Vt, const float* __restrict__ maskadd,
    void* __restrict__ out, const int* __restrict__ flags) {
  // Pw double buffer: 4 waves x 2 x [32 q][36] u16 = 18432 B (loop)
  // lp 128 f32 at +18432 -> 18944 B total; epilogue cbuf (17408 B) reuses [0,18432)
  __shared__ __align__(16) char smem[18944];
  const int tid = threadIdx.x;
  const int w = tid >> 6, l = tid & 63;
  const int quad = l >> 4, l15 = l & 15;
  const int qt = blockIdx.x, h = blockIdx.y, n = blockIdx.z;
  const int q0 = qt * 32;
  const bool f32o = flags[0] != 0;
  u16* Pw = (u16*)smem + w * 2304;  // two buffers of 1152 shorts

  // Q as B-frags: q = nq*16 + l15, d = kd*32 + quad*8 + j
  const u16* qbase = Qp + (size_t)(n * TT + q0 + l15) * UU + h * DH + quad * 8;
  short8 bq[2][2];
  bq[0][0] = *(const short8*)(qbase);
  bq[0][1] = *(const short8*)(qbase + 32);
  bq[1][0] = *(const short8*)(qbase + 16 * UU);
  bq[1][1] = *(const short8*)(qbase + 16 * UU + 32);

  const u16* kbase = Kp + (size_t)(n * TT + l15) * UU + h * DH + quad * 8;
  const u16* vbase = Vt + (size_t)((n * HH + h) * DH + l15) * TT + quad * 8;
  const float* mbase = maskadd + n * TT;

  f32x4 o[2][4];  // [q-tile][dh-tile]
  float lsum[2] = {0.0f, 0.0f};
#pragma unroll
  for (int nq = 0; nq < 2; ++nq)
#pragma unroll
    for (int ni = 0; ni < 4; ++ni)
#pragma unroll
      for (int r = 0; r < 4; ++r) o[nq][ni][r] = 0.0f;

  // ---- prologue: S[0] -> P[0] in buf0; start K[1] ----
  short8 ak[2][2];
#pragma unroll
  for (int kt = 0; kt < 2; ++kt)
#pragma unroll
    for (int kd = 0; kd < 2; ++kd)
      ak[kt][kd] = *(const short8*)(kbase + (size_t)(w * 256 + kt * 16) * UU + kd * 32);
  {
    f32x4 s[2][2];
#pragma unroll
    for (int kt = 0; kt < 2; ++kt)
#pragma unroll
      for (int nq = 0; nq < 2; ++nq) {
#pragma unroll
        for (int r = 0; r < 4; ++r) s[kt][nq][r] = 0.0f;
#pragma unroll
        for (int kd = 0; kd < 2; ++kd)
          s[kt][nq] = __builtin_amdgcn_mfma_f32_16x16x32_bf16(
              ak[kt][kd], bq[nq][kd], s[kt][nq], 0, 0, 0);
      }
    // start K[1] loads before the exp stage
#pragma unroll
    for (int kt = 0; kt < 2; ++kt)
#pragma unroll
      for (int kd = 0; kd < 2; ++kd)
        ak[kt][kd] = *(const short8*)(kbase + (size_t)(w * 256 + 32 + kt * 16) * UU + kd * 32);
    float4 mk[2];
    mk[0] = *(const float4*)&mbase[w * 256 + quad * 4];
    mk[1] = *(const float4*)&mbase[w * 256 + 16 + quad * 4];
#pragma unroll
    for (int kt = 0; kt < 2; ++kt)
#pragma unroll
      for (int nq = 0; nq < 2; ++nq) {
        float e0 = ex2(s[kt][nq][0] + mk[kt].x);
        float e1 = ex2(s[kt][nq][1] + mk[kt].y);
        float e2 = ex2(s[kt][nq][2] + mk[kt].z);
        float e3 = ex2(s[kt][nq][3] + mk[kt].w);
        lsum[nq] += (e0 + e1) + (e2 + e3);
        uint2 pk = make_uint2(pk_bf16(e0, e1), pk_bf16(e2, e3));
        *(uint2*)&Pw[(nq * 16 + l15) * 36 + kt * 16 + quad * 4] = pk;
      }
  }

  // ---- pipelined main loop ----
#pragma unroll
  for (int it = 0; it < 8; ++it) {
    const int kb = w * 256 + it * 32;
    u16* Pr = Pw + (it & 1) * 1152;
    // read P[it] (write was a full iteration ago)
    short8 ap[2];
#pragma unroll
    for (int nq = 0; nq < 2; ++nq) {
      short4v lo = *(const short4v*)&Pr[(nq * 16 + l15) * 36 + quad * 8];
      short4v hi = *(const short4v*)&Pr[(nq * 16 + l15) * 36 + quad * 8 + 4];
      union { short8 v8; short4v v4[2]; } u;
      u.v4[0] = lo; u.v4[1] = hi;
      ap[nq] = u.v8;
    }
    // V[it] frags (vm wait covered by the S/exp stage below)
    short8 vf[4];
#pragma unroll
    for (int ni = 0; ni < 4; ++ni)
      vf[ni] = *(const short8*)(vbase + (size_t)(ni * 16) * TT + kb);

    if (it < 7) {
      // S[it+1] from K tile loaded last iteration
      f32x4 s[2][2];
#pragma unroll
      for (int kt = 0; kt < 2; ++kt)
#pragma unroll
        for (int nq = 0; nq < 2; ++nq) {
#pragma unroll
          for (int r = 0; r < 4; ++r) s[kt][nq][r] = 0.0f;
#pragma unroll
          for (int kd = 0; kd < 2; ++kd)
            s[kt][nq] = __builtin_amdgcn_mfma_f32_16x16x32_bf16(
                ak[kt][kd], bq[nq][kd], s[kt][nq], 0, 0, 0);
        }
      if (it < 6) {
        const int kb2 = kb + 64;
#pragma unroll
        for (int kt = 0; kt < 2; ++kt)
#pragma unroll
          for (int kd = 0; kd < 2; ++kd)
            ak[kt][kd] = *(const short8*)(kbase + (size_t)(kb2 + kt * 16) * UU + kd * 32);
      }
      float4 mk[2];
      mk[0] = *(const float4*)&mbase[kb + 32 + quad * 4];
      mk[1] = *(const float4*)&mbase[kb + 48 + quad * 4];
      u16* Pn = Pw + ((it + 1) & 1) * 1152;
#pragma unroll
      for (int kt = 0; kt < 2; ++kt)
#pragma unroll
        for (int nq = 0; nq < 2; ++nq) {
          float e0 = ex2(s[kt][nq][0] + mk[kt].x);
          float e1 = ex2(s[kt][nq][1] + mk[kt].y);
          float e2 = ex2(s[kt][nq][2] + mk[kt].z);
          float e3 = ex2(s[kt][nq][3] + mk[kt].w);
          lsum[nq] += (e0 + e1) + (e2 + e3);
          uint2 pk = make_uint2(pk_bf16(e0, e1), pk_bf16(e2, e3));
          *(uint2*)&Pn[(nq * 16 + l15) * 36 + kt * 16 + quad * 4] = pk;
        }
    }

    // PV[it]
#pragma unroll
    for (int nq = 0; nq < 2; ++nq)
#pragma unroll
      for (int ni = 0; ni < 4; ++ni)
        o[nq][ni] = __builtin_amdgcn_mfma_f32_16x16x32_bf16(
            ap[nq], vf[ni], o[nq][ni], 0, 0, 0);
  }

  // per-wave row sums: butterfly across the 4 quads
#pragma unroll
  for (int nq = 0; nq < 2; ++nq) {
    lsum[nq] += __shfl_xor(lsum[nq], 16);
    lsum[nq] += __shfl_xor(lsum[nq], 32);
  }

  float* lp = (float*)(smem + 18432);  // disjoint from Pw and cbuf
  if (quad == 0) {
    lp[w * 32 + l15] = lsum[0];
    lp[w * 32 + 16 + l15] = lsum[1];
  }
  __syncthreads();  // Pw region about to be reused as cbuf

  // chunked O-partial merge: 2 chunks of 16 q-rows, 4 x 16 x 68 f32 buffer
  float* cbuf = (float*)smem;
#pragma unroll
  for (int c = 0; c < 2; ++c) {
    float* Ow = cbuf + w * (16 * 68);
#pragma unroll
    for (int ni = 0; ni < 4; ++ni)
#pragma unroll
      for (int r = 0; r < 4; ++r)
        Ow[(quad * 4 + r) * 68 + ni * 16 + l15] = o[c][ni][r];
    __syncthreads();
    for (int i = tid; i < 16 * 64; i += 256) {
      int q = i >> 6, j = i & 63;
      float s = cbuf[0 * 1088 + q * 68 + j] + cbuf[1 * 1088 + q * 68 + j] +
                cbuf[2 * 1088 + q * 68 + j] + cbuf[3 * 1088 + q * 68 + j];
      int qg = c * 16 + q;
      float lsum4 = lp[qg] + lp[32 + qg] + lp[64 + qg] + lp[96 + qg];
      float v = s / lsum4;
      size_t idx = (size_t)(n * TT + q0 + qg) * UU + h * DH + j;
      if (f32o) ((float*)out)[idx] = v;
      else ((u16*)out)[idx] = f32_to_bf16(v);
    }
    __syncthreads();
  }
}

// ---------- launcher ----------
extern "C" void kernel_launch(void* const* d_in, const int* in_sizes, int n_in,
                              void* d_out, int out_size, void* d_ws, size_t ws_size,
                              hipStream_t stream) {
  const void* query = d_in[0];
  const void* key   = d_in[1];
  const void* mask  = d_in[2];
  const void* Wq    = d_in[3];
  const void* Wk    = d_in[4];
  const void* Wv    = d_in[5];

  char* base = (char*)d_ws;
  int* flags = (int*)base;
  float* maskadd = (float*)(base + 256);                  // 32 KB
  u16* Wt  = (u16*)(base + 64 * 1024);                    // 1.5 MB
  u16* Xq  = Wt + (size_t)3 * DD * UU;                    // 8 MB
  u16* Xk  = Xq + (size_t)NB * TT * DD;                   // 8 MB
  u16* Qp  = Xk + (size_t)NB * TT * DD;                   // 8 MB
  u16* Kp  = Qp + (size_t)NB * TT * UU;                   // 8 MB
  u16* Vtp = Kp + (size_t)NB * TT * UU;                   // 8 MB

  prep_kernel<<<CONV_BLOCKS + WT_BLOCKS + MASK_BLOCKS, 256, 0, stream>>>(
      query, key, Wq, Wk, Wv, mask, Xq, Xk, Wt, maskadd, flags);

  dim3 pgrid(NB * TT / 128, UU / 128, 3);  // (64, 4, 3)
  proj_mfma<<<pgrid, 256, 0, stream>>>(query, key, Xq, Xk, Wt, Qp, Kp, Vtp, flags);

  dim3 agrid(TT / 32, HH, NB);  // (32, 8, 8)
  attn_mfma<<<agrid, 256, 0, stream>>>(Qp, Kp, Vtp, maskadd, d_out, flags);
}